// Round 7
// baseline (1422.677 us; speedup 1.0000x reference)
//
#include <hip/hip_runtime.h>
#include <hip/hip_bf16.h>

using short8  = __attribute__((ext_vector_type(8))) short;
using float4v = __attribute__((ext_vector_type(4))) float;
using uint2v  = __attribute__((ext_vector_type(2))) unsigned int;
using u32 = unsigned int;
using u16 = unsigned short;

#define MFMA(a,b,cc) __builtin_amdgcn_mfma_f32_16x16x32_bf16((a),(b),(cc),0,0,0)
// barrier draining only LDS ops: global prefetch stays in flight across it
#define PIPE_BARRIER() asm volatile("s_waitcnt lgkmcnt(0)\n\ts_barrier" ::: "memory")
#define LOG2E 1.44269504088896340736f

static __device__ __forceinline__ float fexp2(float x){ return __builtin_amdgcn_exp2f(x); }
static __device__ __forceinline__ float frcp(float x){ return __builtin_amdgcn_rcpf(x); }

static __device__ __forceinline__ short f2bf(float f){
  __hip_bfloat16 h = __float2bfloat16(f);
  return __builtin_bit_cast(short, h);
}
static __device__ __forceinline__ short8 load_bf8(const float* p){
  short8 v;
#pragma unroll
  for (int j = 0; j < 8; ++j) v[j] = f2bf(p[j]);
  return v;
}
static __device__ __forceinline__ float bflo(u32 d){ return __builtin_bit_cast(float, d << 16); }
static __device__ __forceinline__ float bfhi(u32 d){ return __builtin_bit_cast(float, d & 0xffff0000u); }

// single-cell gate math: 10 trans
static __device__ __forceinline__ float gates1(float ai, float af, float ag, float ao, float& cst){
  float iv = frcp(1.f + fexp2(-LOG2E * ai));
  float fv = frcp(1.f + fexp2(-LOG2E * af));
  float ov = frcp(1.f + fexp2(-LOG2E * ao));
  float gv = 1.f - 2.f * frcp(1.f + fexp2((2.f*LOG2E) * ag));
  float cn = fv * cst + iv * gv;
  cst = cn;
  float tc = 1.f - 2.f * frcp(1.f + fexp2((2.f*LOG2E) * cn));
  return ov * tc;
}

// ---------------- GEMM producer wave: xg(tg) -> LDS slot WS ----------------
// Consumes x(tg) from the register ring, refills ring with x(tg+1).
// Writes xgb[WS][row r][unit u] = {i|f, g|o} bf16-packed (zero-conflict b64s).
template<int WS>
static __device__ __forceinline__ void gm_step(int tg, const float* xrow,
    float4v (&xr)[4][2], const short8 (&wg)[4][4],
    u32 (&xgb)[4][4][132], int lane, int wl)
{
  // convert ring (x[tg]) -> bf16 A-frags
  short8 xb[4];
#pragma unroll
  for (int kk = 0; kk < 4; ++kk){
#pragma unroll
    for (int j = 0; j < 4; ++j){ xb[kk][j] = f2bf(xr[kk][0][j]); xb[kk][4+j] = f2bf(xr[kk][1][j]); }
  }
  // refill ring with x[tg+1] (clamped; only batch lanes c<4 carry real data)
  if (xrow){
    int tn = tg + 1; if (tn > 511) tn = 511;
    const float* nx = xrow + (size_t)tn * 128;
#pragma unroll
    for (int kk = 0; kk < 4; ++kk){
      xr[kk][0] = *(const float4v*)(nx + kk*32);
      xr[kk][1] = *(const float4v*)(nx + kk*32 + 4);
    }
  }
  float4v acc[4];
#pragma unroll
  for (int gt = 0; gt < 4; ++gt) acc[gt] = (float4v){0.f,0.f,0.f,0.f};
#pragma unroll
  for (int kk = 0; kk < 4; ++kk){
    acc[0] = MFMA(xb[kk], wg[0][kk], acc[0]);
    acc[1] = MFMA(xb[kk], wg[1][kk], acc[1]);
    acc[2] = MFMA(xb[kk], wg[2][kk], acc[2]);
    acc[3] = MFMA(xb[kk], wg[3][kk], acc[3]);
  }
  // rows 0-3 live in lanes 0-15 (reg r = row); col = lane = unit offset
  if (lane < 16){
#pragma unroll
    for (int r = 0; r < 4; ++r){
      u32 d0 = (u32)(u16)f2bf(acc[0][r]) | ((u32)(u16)f2bf(acc[1][r]) << 16);
      u32 d1 = (u32)(u16)f2bf(acc[2][r]) | ((u32)(u16)f2bf(acc[3][r]) << 16);
      uint2v dv = {d0, d1};
      *(uint2v*)&xgb[WS][r][(wl*16 + lane)*2] = dv;
    }
  }
}

// ---------------- layer-0 wave step (t = window w; parity/slot static) -----
template<int OFF>
static __device__ __forceinline__ void l0_step(
    const u32 (&xgb)[4][4][132],
    const short8 (&wh)[4][2], const float (&bs)[4],
    float& cst, __hip_bfloat16 (&h0s)[2][16][72],
    float (*tp)[20], int lane, int c, int kg, int wl)
{
  constexpr int P  = OFF & 1;   // h0 buffer parity
  constexpr int RS = OFF;       // xg LDS slot = w & 3
  short8 hf0 = *(const short8*)&h0s[P^1][c][kg*8];
  short8 hf1 = *(const short8*)&h0s[P^1][c][32 + kg*8];
  uint2v xgd = *(const uint2v*)&xgb[RS][kg][(wl*16 + c)*2];
  float4v av[4];
#pragma unroll
  for (int gt = 0; gt < 4; ++gt) av[gt] = (float4v){0.f,0.f,0.f,0.f};
  av[0] = MFMA(hf0, wh[0][0], av[0]); av[1] = MFMA(hf0, wh[1][0], av[1]);
  av[2] = MFMA(hf0, wh[2][0], av[2]); av[3] = MFMA(hf0, wh[3][0], av[3]);
  av[0] = MFMA(hf1, wh[0][1], av[0]); av[1] = MFMA(hf1, wh[1][1], av[1]);
  av[2] = MFMA(hf1, wh[2][1], av[2]); av[3] = MFMA(hf1, wh[3][1], av[3]);
  // redistribute: lanes 0-15 (rows 0-3 valid) -> 1 cell/lane
  if (lane < 16){
#pragma unroll
    for (int r = 0; r < 4; ++r){
      float4v t_ = {av[0][r], av[1][r], av[2][r], av[3][r]};
      *(float4v*)&tp[lane][r*4] = t_;
    }
  }
  float4v g4 = *(const float4v*)&tp[c][kg*4];
  float ai = g4[0] + bs[0] + bflo(xgd[0]);
  float af = g4[1] + bs[1] + bfhi(xgd[0]);
  float ag = g4[2] + bs[2] + bflo(xgd[1]);
  float ao = g4[3] + bs[3] + bfhi(xgd[1]);
  float hv = gates1(ai, af, ag, ao, cst);
  h0s[P][kg][wl*16 + c] = __float2bfloat16(hv);
}

// ---------------- layer-1 wave step (t1 = w-1; TPAR = t1 & 1) --------------
template<int TPAR>
static __device__ __forceinline__ void l1_step(bool last,
    const short8 (&wi)[4][2], const short8 (&wh)[4][2], const float (&bs)[4],
    float& cst,
    const __hip_bfloat16 (&h0s)[2][16][72], __hip_bfloat16 (&h1s)[2][16][72],
    float (*tp)[20], float (*hfin)[64], int lane, int c, int kg, int wl)
{
  short8 a0 = *(const short8*)&h0s[TPAR][c][kg*8];
  short8 a1 = *(const short8*)&h0s[TPAR][c][32 + kg*8];
  short8 b0 = *(const short8*)&h1s[TPAR^1][c][kg*8];
  short8 b1 = *(const short8*)&h1s[TPAR^1][c][32 + kg*8];
  float4v av[4];
#pragma unroll
  for (int gt = 0; gt < 4; ++gt) av[gt] = (float4v){0.f,0.f,0.f,0.f};
  av[0] = MFMA(a0, wi[0][0], av[0]); av[1] = MFMA(a0, wi[1][0], av[1]);
  av[2] = MFMA(a0, wi[2][0], av[2]); av[3] = MFMA(a0, wi[3][0], av[3]);
  av[0] = MFMA(a1, wi[0][1], av[0]); av[1] = MFMA(a1, wi[1][1], av[1]);
  av[2] = MFMA(a1, wi[2][1], av[2]); av[3] = MFMA(a1, wi[3][1], av[3]);
  av[0] = MFMA(b0, wh[0][0], av[0]); av[1] = MFMA(b0, wh[1][0], av[1]);
  av[2] = MFMA(b0, wh[2][0], av[2]); av[3] = MFMA(b0, wh[3][0], av[3]);
  av[0] = MFMA(b1, wh[0][1], av[0]); av[1] = MFMA(b1, wh[1][1], av[1]);
  av[2] = MFMA(b1, wh[2][1], av[2]); av[3] = MFMA(b1, wh[3][1], av[3]);
  if (lane < 16){
#pragma unroll
    for (int r = 0; r < 4; ++r){
      float4v t_ = {av[0][r], av[1][r], av[2][r], av[3][r]};
      *(float4v*)&tp[lane][r*4] = t_;
    }
  }
  float4v g4 = *(const float4v*)&tp[c][kg*4];
  float hv = gates1(g4[0]+bs[0], g4[1]+bs[1], g4[2]+bs[2], g4[3]+bs[3], cst);
  h1s[TPAR][kg][wl*16 + c] = __float2bfloat16(hv);
  if (last) hfin[kg][wl*16 + c] = hv;
}

// ============================================================================
// Fused single kernel: 256 blocks x 4 batch rows, 768 threads (12 waves).
// Waves 0-3: layer0 (step w). Waves 4-7: layer1 (step w-1).
// Waves 8-11: GEMM producers: xg(w+2) = bf16(x_{w+2} @ Wih0^T) -> LDS ring.
// One lgkm-only barrier per window; x prefetch stays in flight across it.
// ============================================================================
__global__ __launch_bounds__(768, 3) void lstm_fused(
    const float* __restrict__ x,
    const float* __restrict__ Wih0, const float* __restrict__ Whh0,
    const float* __restrict__ bih0, const float* __restrict__ bhh0,
    const float* __restrict__ Wih1, const float* __restrict__ Whh1,
    const float* __restrict__ bih1, const float* __restrict__ bhh1,
    const float* __restrict__ fcw,  const float* __restrict__ fcb,
    float* __restrict__ out)
{
  constexpr int T = 512;
  const int tid  = threadIdx.x;
  const int lane = tid & 63;
  const int wv   = tid >> 6;     // 0..11
  const int grp  = wv >> 2;      // 0: L0, 1: L1, 2: GEMM
  const int wl   = wv & 3;
  const int c    = lane & 15;
  const int kg   = lane >> 4;
  const int bblk = blockIdx.x;   // 4-batch block (0..255)

  __shared__ __align__(16) __hip_bfloat16 h0s[2][16][72];
  __shared__ __align__(16) __hip_bfloat16 h1s[2][16][72];
  __shared__ __align__(16) u32  xgb[4][4][132];   // [slot][row][unit*2+pair]
  __shared__ __align__(16) float tmp[2][4][16][20];
  __shared__ float hfin[4][64];

  { // zero h buffers (rows 4-15 must stay zero: they feed MFMA A-frags)
    __hip_bfloat16 z = __float2bfloat16(0.f);
    for (int i = tid; i < 2*16*72; i += 768){
      (&h0s[0][0][0])[i] = z;
      (&h1s[0][0][0])[i] = z;
    }
  }

  // ---- per-role weight fragments ----
  short8 wi[4][2], wh[4][2], wg[4][4];
  float  bs[4];
  const int urow = wl*16 + c;
  if (grp == 0){
#pragma unroll
    for (int gt = 0; gt < 4; ++gt){
      const int row = gt*64 + urow;
#pragma unroll
      for (int kk = 0; kk < 2; ++kk)
        wh[gt][kk] = load_bf8(Whh0 + row*64 + kk*32 + kg*8);
      bs[gt] = bih0[row] + bhh0[row];
    }
  } else if (grp == 1){
#pragma unroll
    for (int gt = 0; gt < 4; ++gt){
      const int row = gt*64 + urow;
#pragma unroll
      for (int kk = 0; kk < 2; ++kk){
        wi[gt][kk] = load_bf8(Wih1 + row*64 + kk*32 + kg*8);
        wh[gt][kk] = load_bf8(Whh1 + row*64 + kk*32 + kg*8);
      }
      bs[gt] = bih1[row] + bhh1[row];
    }
  } else {
#pragma unroll
    for (int gt = 0; gt < 4; ++gt){
      const int row = gt*64 + urow;
#pragma unroll
      for (int kk = 0; kk < 4; ++kk)
        wg[gt][kk] = load_bf8(Wih0 + row*128 + kk*32 + kg*8);
    }
  }

  // ---- GEMM x register ring (1 slot, prefetch distance ~1 window) ----
  const float* xrow = nullptr;
  float4v xr[4][2];
  if (grp == 2 && c < 4){
    xrow = x + (size_t)(bblk*4 + c) * T * 128 + kg*8;
#pragma unroll
    for (int kk = 0; kk < 4; ++kk){
      xr[kk][0] = *(const float4v*)(xrow + kk*32);
      xr[kk][1] = *(const float4v*)(xrow + kk*32 + 4);
    }
  }
  float cst = 0.f;
  float (*tp)[20] = tmp[grp & 1][wl];   // rec waves only (grp 0/1)

  __syncthreads();  // zero-init visible

  // ---- prologue: fill xg slots 0,1 (t=0,1) ----
  if (grp == 2) gm_step<0>(0, xrow, xr, wg, xgb, lane, wl);
  PIPE_BARRIER();
  if (grp == 2) gm_step<1>(1, xrow, xr, wg, xgb, lane, wl);
  PIPE_BARRIER();

  // ---- main: 512 windows, unrolled x4 for static parity/slots ----
  for (int lt = 0; lt < T; lt += 4){
    // OFF=0: L0 t=lt (P0, slot0), L1 t1=lt-1 (par1), GEMM tg=lt+2 -> slot2
    if (grp == 0) l0_step<0>(xgb, wh, bs, cst, h0s, tp, lane, c, kg, wl);
    else if (grp == 1){ if (lt > 0) l1_step<1>(false, wi, wh, bs, cst, h0s, h1s, tp, hfin, lane, c, kg, wl); }
    else if (lt + 0 <= 509) gm_step<2>(lt+2, xrow, xr, wg, xgb, lane, wl);
    PIPE_BARRIER();
    // OFF=1
    if (grp == 0) l0_step<1>(xgb, wh, bs, cst, h0s, tp, lane, c, kg, wl);
    else if (grp == 1) l1_step<0>(false, wi, wh, bs, cst, h0s, h1s, tp, hfin, lane, c, kg, wl);
    else if (lt + 1 <= 509) gm_step<3>(lt+3, xrow, xr, wg, xgb, lane, wl);
    PIPE_BARRIER();
    // OFF=2
    if (grp == 0) l0_step<2>(xgb, wh, bs, cst, h0s, tp, lane, c, kg, wl);
    else if (grp == 1) l1_step<1>(false, wi, wh, bs, cst, h0s, h1s, tp, hfin, lane, c, kg, wl);
    else if (lt + 2 <= 509) gm_step<0>(lt+4, xrow, xr, wg, xgb, lane, wl);
    PIPE_BARRIER();
    // OFF=3
    if (grp == 0) l0_step<3>(xgb, wh, bs, cst, h0s, tp, lane, c, kg, wl);
    else if (grp == 1) l1_step<0>(false, wi, wh, bs, cst, h0s, h1s, tp, hfin, lane, c, kg, wl);
    else if (lt + 3 <= 509) gm_step<1>(lt+5, xrow, xr, wg, xgb, lane, wl);
    PIPE_BARRIER();
  }
  // epilogue: L1 t1 = 511 (odd parity)
  if (grp == 1)
    l1_step<1>(true, wi, wh, bs, cst, h0s, h1s, tp, hfin, lane, c, kg, wl);
  __syncthreads();

  // FC head: out[b] = sigmoid(h1_last . fcw + fcb)
  if (tid < 4){
    float s = fcb[0];
#pragma unroll
    for (int k = 0; k < 64; ++k) s += hfin[tid][k] * fcw[k];
    out[bblk*4 + tid] = frcp(1.f + fexp2(-LOG2E * s));
  }
}

extern "C" void kernel_launch(void* const* d_in, const int* in_sizes, int n_in,
                              void* d_out, int out_size, void* d_ws, size_t ws_size,
                              hipStream_t stream) {
  const float* x    = (const float*)d_in[0];
  const float* Wih0 = (const float*)d_in[1];
  const float* Whh0 = (const float*)d_in[2];
  const float* bih0 = (const float*)d_in[3];
  const float* bhh0 = (const float*)d_in[4];
  const float* Wih1 = (const float*)d_in[5];
  const float* Whh1 = (const float*)d_in[6];
  const float* bih1 = (const float*)d_in[7];
  const float* bhh1 = (const float*)d_in[8];
  const float* fcw  = (const float*)d_in[9];
  const float* fcb  = (const float*)d_in[10];
  float* out = (float*)d_out;

  hipLaunchKernelGGL(lstm_fused, dim3(256), dim3(768), 0, stream,
                     x, Wih0, Whh0, bih0, bhh0, Wih1, Whh1, bih1, bhh1,
                     fcw, fcb, out);
}

// Round 8
// 417.810 us; speedup vs baseline: 3.4051x; 3.4051x over previous
//
#include <hip/hip_runtime.h>
#include <hip/hip_bf16.h>

using short8  = __attribute__((ext_vector_type(8))) short;
using float4v = __attribute__((ext_vector_type(4))) float;
using uint2v  = __attribute__((ext_vector_type(2))) unsigned int;
using u32 = unsigned int;
using u16 = unsigned short;

#define MFMA(a,b,cc) __builtin_amdgcn_mfma_f32_16x16x32_bf16((a),(b),(cc),0,0,0)
// barrier draining only LDS ops: global prefetch stays in flight across it
#define PIPE_BARRIER() asm volatile("s_waitcnt lgkmcnt(0)\n\ts_barrier" ::: "memory")
#define LOG2E 1.44269504088896340736f

static __device__ __forceinline__ float fexp2(float x){ return __builtin_amdgcn_exp2f(x); }
static __device__ __forceinline__ float frcp(float x){ return __builtin_amdgcn_rcpf(x); }

static __device__ __forceinline__ short f2bf(float f){
  __hip_bfloat16 h = __float2bfloat16(f);
  return __builtin_bit_cast(short, h);
}
static __device__ __forceinline__ short8 load_bf8(const float* p){
  short8 v;
#pragma unroll
  for (int j = 0; j < 8; ++j) v[j] = f2bf(p[j]);
  return v;
}
static __device__ __forceinline__ float bflo(u32 d){ return __builtin_bit_cast(float, d << 16); }
static __device__ __forceinline__ float bfhi(u32 d){ return __builtin_bit_cast(float, d & 0xffff0000u); }

// single-cell gate math: 10 trans
static __device__ __forceinline__ float gates1(float ai, float af, float ag, float ao, float& cst){
  float iv = frcp(1.f + fexp2(-LOG2E * ai));
  float fv = frcp(1.f + fexp2(-LOG2E * af));
  float ov = frcp(1.f + fexp2(-LOG2E * ao));
  float gv = 1.f - 2.f * frcp(1.f + fexp2((2.f*LOG2E) * ag));
  float cn = fv * cst + iv * gv;
  cst = cn;
  float tc = 1.f - 2.f * frcp(1.f + fexp2((2.f*LOG2E) * cn));
  return ov * tc;
}

// ---------------- GEMM producer wave: xg(tg) -> LDS slot WS ----------------
// wA = Wih0 fragments (all 4 k-frags). Consumes x(tg) from the f32 register
// ring, refills ring with x(tg+1). Writes xgb[WS][row][unit] = {i|f, g|o}.
template<int WS>
static __device__ __forceinline__ void gm_step(int tg, const float* xrow,
    float4v (&xr)[4][2], const short8 (&wA)[4][4],
    u32 (&xgb)[4][4][132], int lane, int wl)
{
  short8 xb[4];
#pragma unroll
  for (int kk = 0; kk < 4; ++kk){
#pragma unroll
    for (int j = 0; j < 4; ++j){ xb[kk][j] = f2bf(xr[kk][0][j]); xb[kk][4+j] = f2bf(xr[kk][1][j]); }
  }
  if (xrow){
    int tn = tg + 1; if (tn > 511) tn = 511;
    const float* nx = xrow + (size_t)tn * 128;
#pragma unroll
    for (int kk = 0; kk < 4; ++kk){
      xr[kk][0] = *(const float4v*)(nx + kk*32);
      xr[kk][1] = *(const float4v*)(nx + kk*32 + 4);
    }
  }
  float4v acc[4];
#pragma unroll
  for (int gt = 0; gt < 4; ++gt) acc[gt] = (float4v){0.f,0.f,0.f,0.f};
#pragma unroll
  for (int kk = 0; kk < 4; ++kk){
    acc[0] = MFMA(xb[kk], wA[0][kk], acc[0]);
    acc[1] = MFMA(xb[kk], wA[1][kk], acc[1]);
    acc[2] = MFMA(xb[kk], wA[2][kk], acc[2]);
    acc[3] = MFMA(xb[kk], wA[3][kk], acc[3]);
  }
  if (lane < 16){
#pragma unroll
    for (int r = 0; r < 4; ++r){
      u32 d0 = (u32)(u16)f2bf(acc[0][r]) | ((u32)(u16)f2bf(acc[1][r]) << 16);
      u32 d1 = (u32)(u16)f2bf(acc[2][r]) | ((u32)(u16)f2bf(acc[3][r]) << 16);
      uint2v dv = {d0, d1};
      *(uint2v*)&xgb[WS][r][(wl*16 + lane)*2] = dv;
    }
  }
}

// ---------------- layer-0 wave step: wA[gt][0..1] = Whh0 -------------------
template<int OFF>
static __device__ __forceinline__ void l0_step(
    const u32 (&xgb)[4][4][132],
    const short8 (&wA)[4][4], const float (&bs)[4],
    float& cst, __hip_bfloat16 (&h0s)[2][16][72],
    float (*tp)[20], int lane, int c, int kg, int wl)
{
  constexpr int P  = OFF & 1;   // h0 buffer parity
  constexpr int RS = OFF;       // xg LDS slot = t & 3
  short8 hf0 = *(const short8*)&h0s[P^1][c][kg*8];
  short8 hf1 = *(const short8*)&h0s[P^1][c][32 + kg*8];
  uint2v xgd = *(const uint2v*)&xgb[RS][kg][(wl*16 + c)*2];
  float4v av[4];
#pragma unroll
  for (int gt = 0; gt < 4; ++gt) av[gt] = (float4v){0.f,0.f,0.f,0.f};
  av[0] = MFMA(hf0, wA[0][0], av[0]); av[1] = MFMA(hf0, wA[1][0], av[1]);
  av[2] = MFMA(hf0, wA[2][0], av[2]); av[3] = MFMA(hf0, wA[3][0], av[3]);
  av[0] = MFMA(hf1, wA[0][1], av[0]); av[1] = MFMA(hf1, wA[1][1], av[1]);
  av[2] = MFMA(hf1, wA[2][1], av[2]); av[3] = MFMA(hf1, wA[3][1], av[3]);
  if (lane < 16){
#pragma unroll
    for (int r = 0; r < 4; ++r){
      float4v t_ = {av[0][r], av[1][r], av[2][r], av[3][r]};
      *(float4v*)&tp[lane][r*4] = t_;
    }
  }
  float4v g4 = *(const float4v*)&tp[c][kg*4];
  float ai = g4[0] + bs[0] + bflo(xgd[0]);
  float af = g4[1] + bs[1] + bfhi(xgd[0]);
  float ag = g4[2] + bs[2] + bflo(xgd[1]);
  float ao = g4[3] + bs[3] + bfhi(xgd[1]);
  float hv = gates1(ai, af, ag, ao, cst);
  h0s[P][kg][wl*16 + c] = __float2bfloat16(hv);
}

// -------- layer-1 wave step: wA[gt][0..1] = Wih1, wA[gt][2..3] = Whh1 ------
template<int TPAR>
static __device__ __forceinline__ void l1_step(bool last,
    const short8 (&wA)[4][4], const float (&bs)[4],
    float& cst,
    const __hip_bfloat16 (&h0s)[2][16][72], __hip_bfloat16 (&h1s)[2][16][72],
    float (*tp)[20], float (*hfin)[64], int lane, int c, int kg, int wl)
{
  short8 a0 = *(const short8*)&h0s[TPAR][c][kg*8];
  short8 a1 = *(const short8*)&h0s[TPAR][c][32 + kg*8];
  short8 b0 = *(const short8*)&h1s[TPAR^1][c][kg*8];
  short8 b1 = *(const short8*)&h1s[TPAR^1][c][32 + kg*8];
  float4v av[4];
#pragma unroll
  for (int gt = 0; gt < 4; ++gt) av[gt] = (float4v){0.f,0.f,0.f,0.f};
  av[0] = MFMA(a0, wA[0][0], av[0]); av[1] = MFMA(a0, wA[1][0], av[1]);
  av[2] = MFMA(a0, wA[2][0], av[2]); av[3] = MFMA(a0, wA[3][0], av[3]);
  av[0] = MFMA(a1, wA[0][1], av[0]); av[1] = MFMA(a1, wA[1][1], av[1]);
  av[2] = MFMA(a1, wA[2][1], av[2]); av[3] = MFMA(a1, wA[3][1], av[3]);
  av[0] = MFMA(b0, wA[0][2], av[0]); av[1] = MFMA(b0, wA[1][2], av[1]);
  av[2] = MFMA(b0, wA[2][2], av[2]); av[3] = MFMA(b0, wA[3][2], av[3]);
  av[0] = MFMA(b1, wA[0][3], av[0]); av[1] = MFMA(b1, wA[1][3], av[1]);
  av[2] = MFMA(b1, wA[2][3], av[2]); av[3] = MFMA(b1, wA[3][3], av[3]);
  if (lane < 16){
#pragma unroll
    for (int r = 0; r < 4; ++r){
      float4v t_ = {av[0][r], av[1][r], av[2][r], av[3][r]};
      *(float4v*)&tp[lane][r*4] = t_;
    }
  }
  float4v g4 = *(const float4v*)&tp[c][kg*4];
  float hv = gates1(g4[0]+bs[0], g4[1]+bs[1], g4[2]+bs[2], g4[3]+bs[3], cst);
  h1s[TPAR][kg][wl*16 + c] = __float2bfloat16(hv);
  if (last) hfin[kg][wl*16 + c] = hv;
}

// ============================================================================
// Fused single kernel: 256 blocks x 4 batch rows, 768 threads (12 waves).
// Waves 0-3: layer0 (step w). Waves 4-7: layer1 (step w-1).
// Waves 8-11: GEMM producers: xg(w+2) = bf16(x_{w+2} @ Wih0^T) -> LDS ring.
// One lgkm-only barrier per window. Weight regs UNIONED across roles (wA) and
// waves/EU pinned to 3 so the compiler uses the full ~170-VGPR budget
// instead of spilling (round-7 failure: VGPR=84 + 91MB scratch writes).
// ============================================================================
__global__ __attribute__((amdgpu_flat_work_group_size(768, 768), amdgpu_waves_per_eu(3, 3)))
void lstm_fused(
    const float* __restrict__ x,
    const float* __restrict__ Wih0, const float* __restrict__ Whh0,
    const float* __restrict__ bih0, const float* __restrict__ bhh0,
    const float* __restrict__ Wih1, const float* __restrict__ Whh1,
    const float* __restrict__ bih1, const float* __restrict__ bhh1,
    const float* __restrict__ fcw,  const float* __restrict__ fcb,
    float* __restrict__ out)
{
  constexpr int T = 512;
  const int tid  = threadIdx.x;
  const int lane = tid & 63;
  const int wv   = tid >> 6;     // 0..11
  const int grp  = wv >> 2;      // 0: L0, 1: L1, 2: GEMM
  const int wl   = wv & 3;
  const int c    = lane & 15;
  const int kg   = lane >> 4;
  const int bblk = blockIdx.x;   // 4-batch block (0..255)

  __shared__ __align__(16) __hip_bfloat16 h0s[2][16][72];
  __shared__ __align__(16) __hip_bfloat16 h1s[2][16][72];
  __shared__ __align__(16) u32  xgb[4][4][132];   // [slot][row][unit*2+pair]
  __shared__ __align__(16) float tmp[2][4][16][20];
  __shared__ float hfin[4][64];

  { // zero h buffers (rows 4-15 must stay zero: they feed MFMA A-frags)
    __hip_bfloat16 z = __float2bfloat16(0.f);
    for (int i = tid; i < 2*16*72; i += 768){
      (&h0s[0][0][0])[i] = z;
      (&h1s[0][0][0])[i] = z;
    }
  }

  // ---- unified weight fragments (single 64-VGPR array for all roles) ----
  short8 wA[4][4];
  float  bs[4] = {0.f, 0.f, 0.f, 0.f};
  const int urow = wl*16 + c;
  if (grp == 0){
#pragma unroll
    for (int gt = 0; gt < 4; ++gt){
      const int row = gt*64 + urow;
#pragma unroll
      for (int kk = 0; kk < 2; ++kk){
        wA[gt][kk]   = load_bf8(Whh0 + row*64 + kk*32 + kg*8);
        wA[gt][kk+2] = wA[gt][kk];   // keep defined
      }
      bs[gt] = bih0[row] + bhh0[row];
    }
  } else if (grp == 1){
#pragma unroll
    for (int gt = 0; gt < 4; ++gt){
      const int row = gt*64 + urow;
#pragma unroll
      for (int kk = 0; kk < 2; ++kk){
        wA[gt][kk]   = load_bf8(Wih1 + row*64 + kk*32 + kg*8);
        wA[gt][kk+2] = load_bf8(Whh1 + row*64 + kk*32 + kg*8);
      }
      bs[gt] = bih1[row] + bhh1[row];
    }
  } else {
#pragma unroll
    for (int gt = 0; gt < 4; ++gt){
      const int row = gt*64 + urow;
#pragma unroll
      for (int kk = 0; kk < 4; ++kk)
        wA[gt][kk] = load_bf8(Wih0 + row*128 + kk*32 + kg*8);
    }
  }

  // ---- GEMM x register ring (f32, 1 window deep) ----
  const float* xrow = nullptr;
  float4v xr[4][2];
  if (grp == 2){
#pragma unroll
    for (int kk = 0; kk < 4; ++kk){
      xr[kk][0] = (float4v){0.f,0.f,0.f,0.f};
      xr[kk][1] = (float4v){0.f,0.f,0.f,0.f};
    }
    if (c < 4){
      xrow = x + (size_t)(bblk*4 + c) * T * 128 + kg*8;
#pragma unroll
      for (int kk = 0; kk < 4; ++kk){
        xr[kk][0] = *(const float4v*)(xrow + kk*32);
        xr[kk][1] = *(const float4v*)(xrow + kk*32 + 4);
      }
    }
  }
  float cst = 0.f;
  float (*tp)[20] = tmp[grp & 1][wl];   // rec waves only (grp 0/1)

  __syncthreads();  // zero-init visible

  // ---- prologue: fill xg slots 0,1 (t=0,1) ----
  if (grp == 2) gm_step<0>(0, xrow, xr, wA, xgb, lane, wl);
  PIPE_BARRIER();
  if (grp == 2) gm_step<1>(1, xrow, xr, wA, xgb, lane, wl);
  PIPE_BARRIER();

  // ---- main: 512 windows, unrolled x4 for static parity/slots ----
  for (int lt = 0; lt < T; lt += 4){
    if (grp == 0) l0_step<0>(xgb, wA, bs, cst, h0s, tp, lane, c, kg, wl);
    else if (grp == 1){ if (lt > 0) l1_step<1>(false, wA, bs, cst, h0s, h1s, tp, hfin, lane, c, kg, wl); }
    else if (lt + 0 <= 509) gm_step<2>(lt+2, xrow, xr, wA, xgb, lane, wl);
    PIPE_BARRIER();
    if (grp == 0) l0_step<1>(xgb, wA, bs, cst, h0s, tp, lane, c, kg, wl);
    else if (grp == 1) l1_step<0>(false, wA, bs, cst, h0s, h1s, tp, hfin, lane, c, kg, wl);
    else if (lt + 1 <= 509) gm_step<3>(lt+3, xrow, xr, wA, xgb, lane, wl);
    PIPE_BARRIER();
    if (grp == 0) l0_step<2>(xgb, wA, bs, cst, h0s, tp, lane, c, kg, wl);
    else if (grp == 1) l1_step<1>(false, wA, bs, cst, h0s, h1s, tp, hfin, lane, c, kg, wl);
    else if (lt + 2 <= 509) gm_step<0>(lt+4, xrow, xr, wA, xgb, lane, wl);
    PIPE_BARRIER();
    if (grp == 0) l0_step<3>(xgb, wA, bs, cst, h0s, tp, lane, c, kg, wl);
    else if (grp == 1) l1_step<0>(false, wA, bs, cst, h0s, h1s, tp, hfin, lane, c, kg, wl);
    else if (lt + 3 <= 509) gm_step<1>(lt+5, xrow, xr, wA, xgb, lane, wl);
    PIPE_BARRIER();
  }
  // epilogue: L1 t1 = 511 (odd parity)
  if (grp == 1)
    l1_step<1>(true, wA, bs, cst, h0s, h1s, tp, hfin, lane, c, kg, wl);
  __syncthreads();

  // FC head: out[b] = sigmoid(h1_last . fcw + fcb)
  if (tid < 4){
    float s = fcb[0];
#pragma unroll
    for (int k = 0; k < 64; ++k) s += hfin[tid][k] * fcw[k];
    out[bblk*4 + tid] = frcp(1.f + fexp2(-LOG2E * s));
  }
}

extern "C" void kernel_launch(void* const* d_in, const int* in_sizes, int n_in,
                              void* d_out, int out_size, void* d_ws, size_t ws_size,
                              hipStream_t stream) {
  const float* x    = (const float*)d_in[0];
  const float* Wih0 = (const float*)d_in[1];
  const float* Whh0 = (const float*)d_in[2];
  const float* bih0 = (const float*)d_in[3];
  const float* bhh0 = (const float*)d_in[4];
  const float* Wih1 = (const float*)d_in[5];
  const float* Whh1 = (const float*)d_in[6];
  const float* bih1 = (const float*)d_in[7];
  const float* bhh1 = (const float*)d_in[8];
  const float* fcw  = (const float*)d_in[9];
  const float* fcb  = (const float*)d_in[10];
  float* out = (float*)d_out;

  hipLaunchKernelGGL(lstm_fused, dim3(256), dim3(768), 0, stream,
                     x, Wih0, Whh0, bih0, bhh0, Wih1, Whh1, bih1, bhh1,
                     fcw, fcb, out);
}